// Round 1
// baseline (937.544 us; speedup 1.0000x reference)
//
#include <hip/hip_runtime.h>

typedef __bf16 bf16x8 __attribute__((ext_vector_type(8)));
typedef float  f32x4  __attribute__((ext_vector_type(4)));

#define D_DIM 9984   // 13*768
#define H1P   1024   // H1=1000 padded

__device__ __forceinline__ void gld_lds16(const void* g, void* l) {
  __builtin_amdgcn_global_load_lds((__attribute__((address_space(1))) void*)(g),
                                   (__attribute__((address_space(3))) void*)(l),
                                   16, 0, 0);
}

// ---- W1 [9984][1000] fp32 -> W1T [1024][9984] bf16 (rows >=1000 zeroed) ----
__global__ __launch_bounds__(256) void k_transpose_w1(const float* __restrict__ W1,
                                                      __bf16* __restrict__ W1T) {
  __shared__ float tile[32][33];
  const int bk = blockIdx.x, bn = blockIdx.y;
  const int tx = threadIdx.x, ty = threadIdx.y;
#pragma unroll
  for (int i = 0; i < 4; ++i) {
    const int kk = bk * 32 + ty + i * 8;
    const int nn = bn * 32 + tx;
    tile[ty + i * 8][tx] = (nn < 1000) ? W1[(size_t)kk * 1000 + nn] : 0.f;
  }
  __syncthreads();
#pragma unroll
  for (int i = 0; i < 4; ++i) {
    const int nn = bn * 32 + ty + i * 8;   // row of W1T (n)
    const int kk = bk * 32 + tx;           // col of W1T (k)
    W1T[(size_t)nn * D_DIM + kk] = (__bf16)tile[tx][ty + i * 8];
  }
}

// ---- W2 [1000][40] fp32 -> W2T [64][1024] bf16 (pads zeroed) ----
__global__ void k_prep_w2(const float* __restrict__ W2, __bf16* __restrict__ W2T) {
  const int idx = blockIdx.x * 256 + threadIdx.x;  // 65536 total
  const int j = idx >> 10, k = idx & 1023;
  const float v = (j < 40 && k < 1000) ? W2[k * 40 + j] : 0.f;
  W2T[idx] = (__bf16)v;
}

// ---- GEMM1 fused cvt: h1 = relu(A_fp32 @ W1 + b1) ----
// 128x128 tile, BK=32, 4 waves 2x2, 4x4 frags.
// A: global fp32 -> regs -> cvt -> ds_write (reg-staged, replaces k_cvt_a pass).
// B: global_load_lds bf16.
// Explicit double-buffered LDS, prefetch tile i+1 issued BEFORE computing tile i
// (T3 minimum 2-phase). Grid dim3(8,64): tn fastest so the 8 blocks sharing one
// A-panel are consecutive in dispatch -> concurrent on the 8 XCDs -> L3 serves
// the 8x A-reuse (A fp32 fetched from HBM ~once).
__global__ __launch_bounds__(256) void k_gemm1f(const float* __restrict__ A,
                                                const __bf16* __restrict__ BT,
                                                const float* __restrict__ b1,
                                                __bf16* __restrict__ C) {
  __shared__ __align__(16) __bf16 As[2][128 * 32];
  __shared__ __align__(16) __bf16 Bs[2][128 * 32];
  const int tid  = threadIdx.x;
  const int lane = tid & 63;
  const int wid  = tid >> 6;
  const int tn = blockIdx.x, tm = blockIdx.y;
  const int wm = wid & 1, wn = wid >> 1;

  // A reg-staging: thread t covers row (t>>1), 16 cols at (t&1)*16. 256 thr = 128 rows x 32 cols.
  const int arow = tid >> 1;
  const int acol = (tid & 1) * 16;
  const float* ag = A + (size_t)(tm * 128 + arow) * D_DIM + acol;
  const int aoff = arow * 32 + acol;

  // B staging via gld_lds: wave w stages row-chunks 2w, 2w+1 (16 rows x 32 cols each).
  const int c0 = wid * 2, c1 = c0 + 1;
  const int lr = lane >> 2;
  const int lc = (lane & 3) * 8;
  const __bf16* bg0 = BT + (size_t)(tn * 128 + c0 * 16 + lr) * D_DIM + lc;
  const __bf16* bg1 = BT + (size_t)(tn * 128 + c1 * 16 + lr) * D_DIM + lc;
  const int bo0 = c0 * 16 * 32, bo1 = c1 * 16 * 32;

  const int fr = lane & 15;
  const int kq = (lane >> 4) * 8;
  f32x4 acc[4][4] = {};

  // prologue: stage tile 0 into buffer 0
  float4 pa[4];
  {
    const float4* ap = (const float4*)ag;
    pa[0] = ap[0]; pa[1] = ap[1]; pa[2] = ap[2]; pa[3] = ap[3];
  }
  gld_lds16(bg0, &Bs[0][bo0]);
  gld_lds16(bg1, &Bs[0][bo1]);
  {
    const float* pf = (const float*)pa;
    bf16x8 w0, w1;
#pragma unroll
    for (int j = 0; j < 8; ++j) { w0[j] = (__bf16)pf[j]; w1[j] = (__bf16)pf[j + 8]; }
    *(bf16x8*)&As[0][aoff]     = w0;
    *(bf16x8*)&As[0][aoff + 8] = w1;
  }
  __syncthreads();

  for (int i = 0; i < 312; ++i) {
    const int cur = i & 1, nxt = cur ^ 1;
    // ---- issue next-tile staging FIRST (in flight across this iter's MFMA) ----
    if (i < 311) {
      const size_t k0n = (size_t)(i + 1) * 32;
      const float4* ap = (const float4*)(ag + k0n);     // A fp32 -> regs (issued early)
      pa[0] = ap[0]; pa[1] = ap[1]; pa[2] = ap[2]; pa[3] = ap[3];
      gld_lds16(bg0 + k0n, &Bs[nxt][bo0]);              // B -> LDS (async)
      gld_lds16(bg1 + k0n, &Bs[nxt][bo1]);
    }
    // ---- compute current tile ----
    bf16x8 af[4], bfr[4];
#pragma unroll
    for (int mi = 0; mi < 4; ++mi)
      af[mi] = *(const bf16x8*)&As[cur][(wm * 64 + mi * 16 + fr) * 32 + kq];
#pragma unroll
    for (int ni = 0; ni < 4; ++ni)
      bfr[ni] = *(const bf16x8*)&Bs[cur][(wn * 64 + ni * 16 + fr) * 32 + kq];
#pragma unroll
    for (int mi = 0; mi < 4; ++mi)
#pragma unroll
      for (int ni = 0; ni < 4; ++ni)
        acc[mi][ni] = __builtin_amdgcn_mfma_f32_16x16x32_bf16(af[mi], bfr[ni], acc[mi][ni], 0, 0, 0);
    // ---- cvt + write A tile i+1 into the other buffer ----
    if (i < 311) {
      const float* pf = (const float*)pa;
      bf16x8 w0, w1;
#pragma unroll
      for (int j = 0; j < 8; ++j) { w0[j] = (__bf16)pf[j]; w1[j] = (__bf16)pf[j + 8]; }
      *(bf16x8*)&As[nxt][aoff]     = w0;
      *(bf16x8*)&As[nxt][aoff + 8] = w1;
    }
    __syncthreads();   // compiler emits vmcnt(0) lgkmcnt(0): gld_lds + ds_write drained
  }

  // D layout: col=lane&15, row=(lane>>4)*4+reg  [m89]
  const int row0 = tm * 128 + wm * 64 + ((lane >> 4) << 2);
  const int col0 = tn * 128 + wn * 64 + fr;
#pragma unroll
  for (int ni = 0; ni < 4; ++ni) {
    const int col = col0 + ni * 16;
    const float bias = (col < 1000) ? b1[col] : 0.f;
#pragma unroll
    for (int mi = 0; mi < 4; ++mi)
#pragma unroll
      for (int r = 0; r < 4; ++r) {
        const float v = acc[mi][ni][r] + bias;
        C[(size_t)(row0 + mi * 16 + r) * H1P + col] = (__bf16)fmaxf(v, 0.f);
      }
  }
}

// ---- GEMM2 + logits fused: lg[m] = sigmoid(relu(h1 @ W2 + b2) @ W3 + b3) ----
// Double-buffered: prefetch tile i+1 before computing tile i (was a fully
// serial 32-iteration load->drain->compute chain).
__global__ __launch_bounds__(256) void k_gemm2l(const __bf16* __restrict__ h1,
                                                const __bf16* __restrict__ W2T,
                                                const float* __restrict__ b2,
                                                const float* __restrict__ W3,
                                                const float* __restrict__ b3,
                                                float* __restrict__ lg) {
  __shared__ __align__(16) __bf16 As[2][64 * 32];
  __shared__ __align__(16) __bf16 Bs[2][64 * 32];
  const int tid  = threadIdx.x;
  const int lane = tid & 63;
  const int wid  = tid >> 6;
  const int bm   = blockIdx.x;

  const __bf16* ag = h1  + (size_t)(bm * 64 + wid * 16 + (lane >> 2)) * H1P + (lane & 3) * 8;
  const __bf16* bg = W2T + (size_t)(wid * 16 + (lane >> 2)) * H1P + (lane & 3) * 8;
  const int wo = wid * 16 * 32;

  const int fr = lane & 15;
  const int kq = (lane >> 4) * 8;
  f32x4 acc[4] = {};

  gld_lds16(ag, &As[0][wo]);
  gld_lds16(bg, &Bs[0][wo]);
  __syncthreads();

  for (int i = 0; i < 32; ++i) {
    const int cur = i & 1;
    if (i < 31) {
      gld_lds16(ag + (i + 1) * 32, &As[cur ^ 1][wo]);
      gld_lds16(bg + (i + 1) * 32, &Bs[cur ^ 1][wo]);
    }
    const bf16x8 a = *(const bf16x8*)&As[cur][(wid * 16 + fr) * 32 + kq];
#pragma unroll
    for (int ni = 0; ni < 4; ++ni) {
      const bf16x8 b = *(const bf16x8*)&Bs[cur][(ni * 16 + fr) * 32 + kq];
      acc[ni] = __builtin_amdgcn_mfma_f32_16x16x32_bf16(a, b, acc[ni], 0, 0, 0);
    }
    __syncthreads();
  }
  // epilogue: lane holds j = ni*16+fr for rows m0..m0+3; reduce over j with W3
  float s[4] = {0.f, 0.f, 0.f, 0.f};
#pragma unroll
  for (int ni = 0; ni < 4; ++ni) {
    const int j = ni * 16 + fr;
    if (j < 40) {
      const float w3 = W3[j], bias = b2[j];
#pragma unroll
      for (int r = 0; r < 4; ++r)
        s[r] += fmaxf(acc[ni][r] + bias, 0.f) * w3;
    }
  }
#pragma unroll
  for (int off = 1; off < 16; off <<= 1)
#pragma unroll
    for (int r = 0; r < 4; ++r)
      s[r] += __shfl_xor(s[r], off, 16);
  if (fr == 0) {
    const int m0 = bm * 64 + wid * 16 + ((lane >> 4) << 2);
    const float b3v = b3[0];
#pragma unroll
    for (int r = 0; r < 4; ++r)
      lg[m0 + r] = 1.f / (1.f + __expf(-(s[r] + b3v)));
  }
}

// ---- ragged gather ----
__global__ void k_gather(const int* __restrict__ ts, const float* __restrict__ lg,
                         float* __restrict__ out) {
  const int t = blockIdx.x * 256 + threadIdx.x;
  const int b = t >> 9;
  const int s = ts[t];
  out[t] = (s > 0 && s < 512) ? lg[(b << 9) + s] : 0.f;
}

extern "C" void kernel_launch(void* const* d_in, const int* in_sizes, int n_in,
                              void* d_out, int out_size, void* d_ws, size_t ws_size,
                              hipStream_t stream) {
  const float* hs = (const float*)d_in[0];
  const int*   ts = (const int*)d_in[1];
  const float* W1 = (const float*)d_in[2];
  const float* b1 = (const float*)d_in[3];
  const float* W2 = (const float*)d_in[4];
  const float* b2 = (const float*)d_in[5];
  const float* W3 = (const float*)d_in[6];
  const float* b3 = (const float*)d_in[7];
  float* out = (float*)d_out;
  char* ws = (char*)d_ws;

  // ws layout (no bf16-A copy needed any more): ~37.4 MiB
  __bf16* W1T = (__bf16*)(ws);                                   // 20,447,232 B
  __bf16* h1  = (__bf16*)(ws + 20447232);                        // 16,777,216 B
  __bf16* W2T = (__bf16*)(ws + 20447232 + 16777216);             //    131,072 B
  float*  lg  = (float*) (ws + 20447232 + 16777216 + 131072);    //     32,768 B

  k_transpose_w1<<<dim3(312, 32), dim3(32, 8), 0, stream>>>(W1, W1T);
  k_prep_w2<<<256, 256, 0, stream>>>(W2, W2T);
  k_gemm1f<<<dim3(8, 64), 256, 0, stream>>>(hs, W1T, b1, h1);
  k_gemm2l<<<128, 256, 0, stream>>>(h1, W2T, b2, W3, b3, lg);
  k_gather<<<32, 256, 0, stream>>>(ts, lg, out);
}

// Round 2
// 760.254 us; speedup vs baseline: 1.2332x; 1.2332x over previous
//
#include <hip/hip_runtime.h>

typedef __bf16 bf16x8 __attribute__((ext_vector_type(8)));
typedef float  f32x4  __attribute__((ext_vector_type(4)));

#define D_DIM 9984   // 13*768
#define H1P   1024   // H1=1000 padded
#define KHALF 4992   // D_DIM/2

__device__ __forceinline__ void gld_lds16(const void* g, void* l) {
  __builtin_amdgcn_global_load_lds((__attribute__((address_space(1))) void*)(g),
                                   (__attribute__((address_space(3))) void*)(l),
                                   16, 0, 0);
}

// ---- merged prep: A cvt (blocks 0..39935) + W1 transpose (39936..49919)
//      + W2T (49920..50175) + b1 pad (50176; only launched in splitK path).
//      doA=0 skips the A-cvt block range (blocks shifted) for the small-ws path.
__global__ __launch_bounds__(256) void k_prep(const float* __restrict__ A,
                                              __bf16* __restrict__ Ab,
                                              const float* __restrict__ W1,
                                              __bf16* __restrict__ W1T,
                                              const float* __restrict__ W2,
                                              __bf16* __restrict__ W2T,
                                              const float* __restrict__ b1,
                                              float* __restrict__ b1p,
                                              int abase_blocks) {
  __shared__ float tile[32][33];
  const int bx  = blockIdx.x;
  const int tid = threadIdx.x;
  if (bx < abase_blocks) {
    // A [8192][9984] fp32 -> bf16, 8 elems/thread
    const size_t t = (size_t)bx * 256 + tid;
    const float4* p = (const float4*)A + t * 2;
    const float4 a = p[0], b = p[1];
    bf16x8 o;
    o[0] = (__bf16)a.x; o[1] = (__bf16)a.y; o[2] = (__bf16)a.z; o[3] = (__bf16)a.w;
    o[4] = (__bf16)b.x; o[5] = (__bf16)b.y; o[6] = (__bf16)b.z; o[7] = (__bf16)b.w;
    *(bf16x8*)(Ab + t * 8) = o;
  } else if (bx < abase_blocks + 9984) {
    // W1 [9984][1000] -> W1T [1024][9984] bf16 (rows >=1000 zeroed)
    const int b = bx - abase_blocks;
    const int bk = b % 312, bn = b / 312;
    const int tx = tid & 31, ty = tid >> 5;
#pragma unroll
    for (int i = 0; i < 4; ++i) {
      const int kk = bk * 32 + ty + i * 8;
      const int nn = bn * 32 + tx;
      tile[ty + i * 8][tx] = (nn < 1000) ? W1[(size_t)kk * 1000 + nn] : 0.f;
    }
    __syncthreads();
#pragma unroll
    for (int i = 0; i < 4; ++i) {
      const int nn = bn * 32 + ty + i * 8;
      const int kk = bk * 32 + tx;
      W1T[(size_t)nn * D_DIM + kk] = (__bf16)tile[tx][ty + i * 8];
    }
  } else if (bx < abase_blocks + 9984 + 256) {
    // W2 [1000][40] -> W2T [64][1024] bf16 (pads zeroed)
    const int idx = (bx - abase_blocks - 9984) * 256 + tid;
    const int j = idx >> 10, k = idx & 1023;
    const float v = (j < 40 && k < 1000) ? W2[k * 40 + j] : 0.f;
    W2T[idx] = (__bf16)v;
  } else {
    // b1 [1000] -> b1p [1024] fp32 (pad zeroed)
    for (int i = tid; i < 1024; i += 256)
      b1p[i] = (i < 1000) ? b1[i] : 0.f;
  }
}

// ---- GEMM1 split-K: P[kh] = Ab[:, kh-half] @ W1T[kh-half]^T  (f32 partials) ----
__global__ __launch_bounds__(256) void k_gemm1s(const __bf16* __restrict__ A,
                                                const __bf16* __restrict__ BT,
                                                float* __restrict__ P) {
  __shared__ __bf16 As[128 * 32];
  __shared__ __bf16 Bs[128 * 32];
  const int tid  = threadIdx.x;
  const int lane = tid & 63;
  const int wid  = tid >> 6;
  const int tm = blockIdx.x, tn = blockIdx.y, kh = blockIdx.z;
  const int wm = wid & 1, wn = wid >> 1;
  const size_t kbase = (size_t)kh * KHALF;

  const int c0 = wid * 2, c1 = c0 + 1;
  const int lr = lane >> 2;
  const int lc = (lane & 3) * 8;
  const __bf16* ag0 = A  + (size_t)(tm * 128 + c0 * 16 + lr) * D_DIM + kbase + lc;
  const __bf16* ag1 = A  + (size_t)(tm * 128 + c1 * 16 + lr) * D_DIM + kbase + lc;
  const __bf16* bg0 = BT + (size_t)(tn * 128 + c0 * 16 + lr) * D_DIM + kbase + lc;
  const __bf16* bg1 = BT + (size_t)(tn * 128 + c1 * 16 + lr) * D_DIM + kbase + lc;
  __bf16* al0 = &As[c0 * 16 * 32];
  __bf16* al1 = &As[c1 * 16 * 32];
  __bf16* bl0 = &Bs[c0 * 16 * 32];
  __bf16* bl1 = &Bs[c1 * 16 * 32];

  const int fr = lane & 15;
  const int kq = (lane >> 4) * 8;
  f32x4 acc[4][4] = {};

  for (int i = 0; i < 156; ++i) {
    const size_t k0 = (size_t)i * 32;
    __syncthreads();
    gld_lds16(ag0 + k0, al0);
    gld_lds16(ag1 + k0, al1);
    gld_lds16(bg0 + k0, bl0);
    gld_lds16(bg1 + k0, bl1);
    __syncthreads();
    bf16x8 af[4], bfr[4];
#pragma unroll
    for (int mi = 0; mi < 4; ++mi)
      af[mi] = *(const bf16x8*)&As[(wm * 64 + mi * 16 + fr) * 32 + kq];
#pragma unroll
    for (int ni = 0; ni < 4; ++ni)
      bfr[ni] = *(const bf16x8*)&Bs[(wn * 64 + ni * 16 + fr) * 32 + kq];
#pragma unroll
    for (int mi = 0; mi < 4; ++mi)
#pragma unroll
      for (int ni = 0; ni < 4; ++ni)
        acc[mi][ni] = __builtin_amdgcn_mfma_f32_16x16x32_bf16(af[mi], bfr[ni], acc[mi][ni], 0, 0, 0);
  }

  float* Pz = P + (size_t)kh * (8192 * H1P);
  const int row0 = tm * 128 + wm * 64 + ((lane >> 4) << 2);
  const int col0 = tn * 128 + wn * 64 + fr;
#pragma unroll
  for (int ni = 0; ni < 4; ++ni) {
    const int col = col0 + ni * 16;
#pragma unroll
    for (int mi = 0; mi < 4; ++mi)
#pragma unroll
      for (int r = 0; r < 4; ++r)
        Pz[(size_t)(row0 + mi * 16 + r) * H1P + col] = acc[mi][ni][r];
  }
}

// ---- GEMM2 + fixup + logits fused (splitK path) ----
__global__ __launch_bounds__(256) void k_gemm2lf(const float* __restrict__ p0,
                                                 const float* __restrict__ p1,
                                                 const __bf16* __restrict__ W2T,
                                                 const float* __restrict__ b1p,
                                                 const float* __restrict__ b2,
                                                 const float* __restrict__ W3,
                                                 const float* __restrict__ b3,
                                                 float* __restrict__ lg) {
  __shared__ __align__(16) __bf16 As[64 * 32];
  __shared__ __align__(16) __bf16 Bs[64 * 32];
  const int tid  = threadIdx.x;
  const int lane = tid & 63;
  const int wid  = tid >> 6;
  const int bm   = blockIdx.x;

  const size_t abase = (size_t)(bm * 64 + wid * 16 + (lane >> 2)) * H1P + (lane & 3) * 8;
  const __bf16* bg = W2T + (size_t)(wid * 16 + (lane >> 2)) * H1P + (lane & 3) * 8;
  const int aoff = (wid * 16 + (lane >> 2)) * 32 + (lane & 3) * 8;
  __bf16* bl = &Bs[wid * 16 * 32];

  const int fr = lane & 15;
  const int kq = (lane >> 4) * 8;
  f32x4 acc[4] = {};

  for (int i = 0; i < 32; ++i) {
    const int k0 = i * 32;
    const float4 x0 = *(const float4*)(p0 + abase + k0);
    const float4 x1 = *(const float4*)(p0 + abase + k0 + 4);
    const float4 y0 = *(const float4*)(p1 + abase + k0);
    const float4 y1 = *(const float4*)(p1 + abase + k0 + 4);
    const float4 c0v = *(const float4*)(b1p + k0 + (lane & 3) * 8);
    const float4 c1v = *(const float4*)(b1p + k0 + (lane & 3) * 8 + 4);
    bf16x8 h;
    h[0] = (__bf16)fmaxf(x0.x + y0.x + c0v.x, 0.f);
    h[1] = (__bf16)fmaxf(x0.y + y0.y + c0v.y, 0.f);
    h[2] = (__bf16)fmaxf(x0.z + y0.z + c0v.z, 0.f);
    h[3] = (__bf16)fmaxf(x0.w + y0.w + c0v.w, 0.f);
    h[4] = (__bf16)fmaxf(x1.x + y1.x + c1v.x, 0.f);
    h[5] = (__bf16)fmaxf(x1.y + y1.y + c1v.y, 0.f);
    h[6] = (__bf16)fmaxf(x1.z + y1.z + c1v.z, 0.f);
    h[7] = (__bf16)fmaxf(x1.w + y1.w + c1v.w, 0.f);
    __syncthreads();
    *(bf16x8*)&As[aoff] = h;
    gld_lds16(bg + k0, bl);
    __syncthreads();
    const bf16x8 a = *(const bf16x8*)&As[(wid * 16 + fr) * 32 + kq];
#pragma unroll
    for (int ni = 0; ni < 4; ++ni) {
      const bf16x8 b = *(const bf16x8*)&Bs[(ni * 16 + fr) * 32 + kq];
      acc[ni] = __builtin_amdgcn_mfma_f32_16x16x32_bf16(a, b, acc[ni], 0, 0, 0);
    }
  }
  float s[4] = {0.f, 0.f, 0.f, 0.f};
#pragma unroll
  for (int ni = 0; ni < 4; ++ni) {
    const int j = ni * 16 + fr;
    if (j < 40) {
      const float w3 = W3[j], bias = b2[j];
#pragma unroll
      for (int r = 0; r < 4; ++r)
        s[r] += fmaxf(acc[ni][r] + bias, 0.f) * w3;
    }
  }
#pragma unroll
  for (int off = 1; off < 16; off <<= 1)
#pragma unroll
    for (int r = 0; r < 4; ++r)
      s[r] += __shfl_xor(s[r], off, 16);
  if (fr == 0) {
    const int m0 = bm * 64 + wid * 16 + ((lane >> 4) << 2);
    const float b3v = b3[0];
#pragma unroll
    for (int r = 0; r < 4; ++r)
      lg[m0 + r] = 1.f / (1.f + __expf(-(s[r] + b3v)));
  }
}

// ---- fallback GEMM1 (round-0 known-good): h1 = relu(Ab @ W1T + b1) bf16 ----
__global__ __launch_bounds__(256) void k_gemm1b(const __bf16* __restrict__ A,
                                                const __bf16* __restrict__ BT,
                                                const float* __restrict__ b1,
                                                __bf16* __restrict__ C) {
  __shared__ __bf16 As[128 * 32];
  __shared__ __bf16 Bs[128 * 32];
  const int tid  = threadIdx.x;
  const int lane = tid & 63;
  const int wid  = tid >> 6;
  const int tm = blockIdx.x, tn = blockIdx.y;
  const int wm = wid & 1, wn = wid >> 1;

  const int c0 = wid * 2, c1 = c0 + 1;
  const int lr = lane >> 2;
  const int lc = (lane & 3) * 8;
  const __bf16* ag0 = A  + (size_t)(tm * 128 + c0 * 16 + lr) * D_DIM + lc;
  const __bf16* ag1 = A  + (size_t)(tm * 128 + c1 * 16 + lr) * D_DIM + lc;
  const __bf16* bg0 = BT + (size_t)(tn * 128 + c0 * 16 + lr) * D_DIM + lc;
  const __bf16* bg1 = BT + (size_t)(tn * 128 + c1 * 16 + lr) * D_DIM + lc;
  __bf16* al0 = &As[c0 * 16 * 32];
  __bf16* al1 = &As[c1 * 16 * 32];
  __bf16* bl0 = &Bs[c0 * 16 * 32];
  __bf16* bl1 = &Bs[c1 * 16 * 32];

  const int fr = lane & 15;
  const int kq = (lane >> 4) * 8;
  f32x4 acc[4][4] = {};

  for (int i = 0; i < 312; ++i) {
    const size_t k0 = (size_t)i * 32;
    __syncthreads();
    gld_lds16(ag0 + k0, al0);
    gld_lds16(ag1 + k0, al1);
    gld_lds16(bg0 + k0, bl0);
    gld_lds16(bg1 + k0, bl1);
    __syncthreads();
    bf16x8 af[4], bfr[4];
#pragma unroll
    for (int mi = 0; mi < 4; ++mi)
      af[mi] = *(const bf16x8*)&As[(wm * 64 + mi * 16 + fr) * 32 + kq];
#pragma unroll
    for (int ni = 0; ni < 4; ++ni)
      bfr[ni] = *(const bf16x8*)&Bs[(wn * 64 + ni * 16 + fr) * 32 + kq];
#pragma unroll
    for (int mi = 0; mi < 4; ++mi)
#pragma unroll
      for (int ni = 0; ni < 4; ++ni)
        acc[mi][ni] = __builtin_amdgcn_mfma_f32_16x16x32_bf16(af[mi], bfr[ni], acc[mi][ni], 0, 0, 0);
  }

  const int row0 = tm * 128 + wm * 64 + ((lane >> 4) << 2);
  const int col0 = tn * 128 + wn * 64 + fr;
#pragma unroll
  for (int ni = 0; ni < 4; ++ni) {
    const int col = col0 + ni * 16;
    const float bias = (col < 1000) ? b1[col] : 0.f;
#pragma unroll
    for (int mi = 0; mi < 4; ++mi)
#pragma unroll
      for (int r = 0; r < 4; ++r) {
        const float v = acc[mi][ni][r] + bias;
        C[(size_t)(row0 + mi * 16 + r) * H1P + col] = (__bf16)fmaxf(v, 0.f);
      }
  }
}

// ---- fallback GEMM2 + logits (reads h1 bf16) ----
__global__ __launch_bounds__(256) void k_gemm2l(const __bf16* __restrict__ h1,
                                                const __bf16* __restrict__ W2T,
                                                const float* __restrict__ b2,
                                                const float* __restrict__ W3,
                                                const float* __restrict__ b3,
                                                float* __restrict__ lg) {
  __shared__ __align__(16) __bf16 As[2][64 * 32];
  __shared__ __align__(16) __bf16 Bs[2][64 * 32];
  const int tid  = threadIdx.x;
  const int lane = tid & 63;
  const int wid  = tid >> 6;
  const int bm   = blockIdx.x;

  const __bf16* ag = h1  + (size_t)(bm * 64 + wid * 16 + (lane >> 2)) * H1P + (lane & 3) * 8;
  const __bf16* bg = W2T + (size_t)(wid * 16 + (lane >> 2)) * H1P + (lane & 3) * 8;
  const int wo = wid * 16 * 32;

  const int fr = lane & 15;
  const int kq = (lane >> 4) * 8;
  f32x4 acc[4] = {};

  gld_lds16(ag, &As[0][wo]);
  gld_lds16(bg, &Bs[0][wo]);
  __syncthreads();

  for (int i = 0; i < 32; ++i) {
    const int cur = i & 1;
    if (i < 31) {
      gld_lds16(ag + (i + 1) * 32, &As[cur ^ 1][wo]);
      gld_lds16(bg + (i + 1) * 32, &Bs[cur ^ 1][wo]);
    }
    const bf16x8 a = *(const bf16x8*)&As[cur][(wid * 16 + fr) * 32 + kq];
#pragma unroll
    for (int ni = 0; ni < 4; ++ni) {
      const bf16x8 b = *(const bf16x8*)&Bs[cur][(ni * 16 + fr) * 32 + kq];
      acc[ni] = __builtin_amdgcn_mfma_f32_16x16x32_bf16(a, b, acc[ni], 0, 0, 0);
    }
    __syncthreads();
  }
  float s[4] = {0.f, 0.f, 0.f, 0.f};
#pragma unroll
  for (int ni = 0; ni < 4; ++ni) {
    const int j = ni * 16 + fr;
    if (j < 40) {
      const float w3 = W3[j], bias = b2[j];
#pragma unroll
      for (int r = 0; r < 4; ++r)
        s[r] += fmaxf(acc[ni][r] + bias, 0.f) * w3;
    }
  }
#pragma unroll
  for (int off = 1; off < 16; off <<= 1)
#pragma unroll
    for (int r = 0; r < 4; ++r)
      s[r] += __shfl_xor(s[r], off, 16);
  if (fr == 0) {
    const int m0 = bm * 64 + wid * 16 + ((lane >> 4) << 2);
    const float b3v = b3[0];
#pragma unroll
    for (int r = 0; r < 4; ++r)
      lg[m0 + r] = 1.f / (1.f + __expf(-(s[r] + b3v)));
  }
}

// ---- fused-cvt GEMM1 for tiny-ws path only (round-1 kernel, correct but slow) ----
__global__ __launch_bounds__(256) void k_gemm1(const float* __restrict__ A,
                                               const __bf16* __restrict__ BT,
                                               const float* __restrict__ b1,
                                               __bf16* __restrict__ C) {
  __shared__ __bf16 As[128 * 32];
  __shared__ __bf16 Bs[128 * 32];
  const int tid  = threadIdx.x;
  const int lane = tid & 63;
  const int wid  = tid >> 6;
  const int tm = blockIdx.x, tn = blockIdx.y;
  const int wm = wid & 1, wn = wid >> 1;

  const int arow = tid >> 1;
  const int acol = (tid & 1) * 16;
  const float* ag = A + (size_t)(tm * 128 + arow) * D_DIM + acol;
  __bf16* asw = &As[arow * 32 + acol];

  const int c0 = wid * 2, c1 = wid * 2 + 1;
  const __bf16* bg0 = BT + (size_t)(tn * 128 + c0 * 16 + (lane >> 2)) * D_DIM + (lane & 3) * 8;
  const __bf16* bg1 = BT + (size_t)(tn * 128 + c1 * 16 + (lane >> 2)) * D_DIM + (lane & 3) * 8;
  __bf16* bl0 = &Bs[c0 * 16 * 32];
  __bf16* bl1 = &Bs[c1 * 16 * 32];

  const int fr = lane & 15;
  const int kq = (lane >> 4) * 8;
  f32x4 acc[4][4] = {};

  float4 pa[4];
  {
    const float4* ap = (const float4*)ag;
    pa[0] = ap[0]; pa[1] = ap[1]; pa[2] = ap[2]; pa[3] = ap[3];
  }
  for (int i = 0; i < 312; ++i) {
    const int k0 = i * 32;
    __syncthreads();
    {
      const float* pf = (const float*)pa;
      bf16x8 w0, w1;
#pragma unroll
      for (int j = 0; j < 8; ++j) { w0[j] = (__bf16)pf[j]; w1[j] = (__bf16)pf[j + 8]; }
      *(bf16x8*)asw       = w0;
      *(bf16x8*)(asw + 8) = w1;
    }
    gld_lds16(bg0 + k0, bl0);
    gld_lds16(bg1 + k0, bl1);
    __syncthreads();
    if (i != 311) {
      const float4* ap = (const float4*)(ag + k0 + 32);
      pa[0] = ap[0]; pa[1] = ap[1]; pa[2] = ap[2]; pa[3] = ap[3];
    }
    bf16x8 af[4], bfr[4];
#pragma unroll
    for (int mi = 0; mi < 4; ++mi)
      af[mi] = *(const bf16x8*)&As[(wm * 64 + mi * 16 + fr) * 32 + kq];
#pragma unroll
    for (int ni = 0; ni < 4; ++ni)
      bfr[ni] = *(const bf16x8*)&Bs[(wn * 64 + ni * 16 + fr) * 32 + kq];
#pragma unroll
    for (int mi = 0; mi < 4; ++mi)
#pragma unroll
      for (int ni = 0; ni < 4; ++ni)
        acc[mi][ni] = __builtin_amdgcn_mfma_f32_16x16x32_bf16(af[mi], bfr[ni], acc[mi][ni], 0, 0, 0);
  }
  const int row0 = tm * 128 + wm * 64 + ((lane >> 4) << 2);
  const int col0 = tn * 128 + wn * 64 + fr;
#pragma unroll
  for (int ni = 0; ni < 4; ++ni) {
    const int col = col0 + ni * 16;
    const float bias = (col < 1000) ? b1[col] : 0.f;
#pragma unroll
    for (int mi = 0; mi < 4; ++mi)
#pragma unroll
      for (int r = 0; r < 4; ++r) {
        const float v = acc[mi][ni][r] + bias;
        C[(size_t)(row0 + mi * 16 + r) * H1P + col] = (__bf16)fmaxf(v, 0.f);
      }
  }
}

// ---- ragged gather ----
__global__ void k_gather(const int* __restrict__ ts, const float* __restrict__ lg,
                         float* __restrict__ out) {
  const int t = blockIdx.x * 256 + threadIdx.x;
  const int b = t >> 9;
  const int s = ts[t];
  out[t] = (s > 0 && s < 512) ? lg[(b << 9) + s] : 0.f;
}

extern "C" void kernel_launch(void* const* d_in, const int* in_sizes, int n_in,
                              void* d_out, int out_size, void* d_ws, size_t ws_size,
                              hipStream_t stream) {
  const float* hs = (const float*)d_in[0];
  const int*   ts = (const int*)d_in[1];
  const float* W1 = (const float*)d_in[2];
  const float* b1 = (const float*)d_in[3];
  const float* W2 = (const float*)d_in[4];
  const float* b2 = (const float*)d_in[5];
  const float* W3 = (const float*)d_in[6];
  const float* b3 = (const float*)d_in[7];
  float* out = (float*)d_out;
  char* ws = (char*)d_ws;

  const size_t ABF   = 163577856;  // 8192*9984*2
  const size_t W1TSZ = 20447232;   // 1024*9984*2
  const size_t PSZ   = 33554432;   // 8192*1024*4
  const size_t NEED2 = ABF + W1TSZ + 2 * PSZ + 131072 + 4096 + 32768;  // ~239.7 MiB
  const size_t NEED1 = ABF + W1TSZ + 16777216 + 131072 + 32768;        // ~191.7 MiB

  if (ws_size >= NEED2) {
    // split-K path: prep(1) + gemm1s(1) + gemm2lf(1) + gather(1) = 4 launches
    __bf16* Ab  = (__bf16*)(ws);
    __bf16* W1T = (__bf16*)(ws + ABF);
    float*  p0  = (float*) (ws + ABF + W1TSZ);
    float*  p1  = (float*) (ws + ABF + W1TSZ + PSZ);
    __bf16* W2T = (__bf16*)(ws + ABF + W1TSZ + 2 * PSZ);
    float*  b1p = (float*) (ws + ABF + W1TSZ + 2 * PSZ + 131072);
    float*  lg  = (float*) (ws + ABF + W1TSZ + 2 * PSZ + 131072 + 4096);

    k_prep<<<39936 + 9984 + 256 + 1, 256, 0, stream>>>(hs, Ab, W1, W1T, W2, W2T, b1, b1p, 39936);
    k_gemm1s<<<dim3(64, 8, 2), 256, 0, stream>>>(Ab, W1T, p0);   // p1 = p0 + PSZ via kh
    k_gemm2lf<<<128, 256, 0, stream>>>(p0, p1, W2T, b1p, b2, W3, b3, lg);
    k_gather<<<32, 256, 0, stream>>>(ts, lg, out);
  } else if (ws_size >= NEED1) {
    // round-0 known-good path with merged prep: 4 launches
    __bf16* Ab  = (__bf16*)(ws);
    __bf16* W1T = (__bf16*)(ws + ABF);
    __bf16* h1  = (__bf16*)(ws + ABF + W1TSZ);
    __bf16* W2T = (__bf16*)(ws + ABF + W1TSZ + 16777216);
    float*  lg  = (float*) (ws + ABF + W1TSZ + 16777216 + 131072);

    k_prep<<<39936 + 9984 + 256, 256, 0, stream>>>(hs, Ab, W1, W1T, W2, W2T, b1, lg, 39936);
    k_gemm1b<<<dim3(64, 8), 256, 0, stream>>>(Ab, W1T, b1, h1);
    k_gemm2l<<<128, 256, 0, stream>>>(h1, W2T, b2, W3, b3, lg);
    k_gather<<<32, 256, 0, stream>>>(ts, lg, out);
  } else {
    // tiny-ws path: no Ab; fused-cvt gemm1 (slow but correct)
    __bf16* W1T = (__bf16*)(ws);
    __bf16* h1  = (__bf16*)(ws + W1TSZ);
    __bf16* W2T = (__bf16*)(ws + W1TSZ + 16777216);
    float*  lg  = (float*) (ws + W1TSZ + 16777216 + 131072);

    k_prep<<<9984 + 256, 256, 0, stream>>>(hs, (__bf16*)W1T /*Ab unused: abase=0*/,
                                           W1, W1T, W2, W2T, b1, lg, 0);
    k_gemm1<<<dim3(64, 8), 256, 0, stream>>>(hs, W1T, b1, h1);
    k_gemm2l<<<128, 256, 0, stream>>>(h1, W2T, b2, W3, b3, lg);
    k_gather<<<32, 256, 0, stream>>>(ts, lg, out);
  }
}

// Round 4
// 705.978 us; speedup vs baseline: 1.3280x; 1.0769x over previous
//
#include <hip/hip_runtime.h>

typedef __bf16 bf16x8 __attribute__((ext_vector_type(8)));
typedef float  f32x4  __attribute__((ext_vector_type(4)));

#define D_DIM 9984   // 13*768
#define H1P   1024   // H1=1000 padded

__device__ __forceinline__ void gld_lds16(const void* g, void* l) {
  __builtin_amdgcn_global_load_lds((__attribute__((address_space(1))) void*)(g),
                                   (__attribute__((address_space(3))) void*)(l),
                                   16, 0, 0);
}

// counted-vmcnt barrier (T4, m218-proven pattern): wait until <=N outstanding
// VMEM ops, then raw barrier; sched_barrier(0) pins following code below it.
#define WAITB(N) do {                                              \
    asm volatile("s_waitcnt vmcnt(" #N ")" ::: "memory");          \
    __builtin_amdgcn_s_barrier();                                  \
    __builtin_amdgcn_sched_barrier(0);                             \
  } while (0)

// ---- merged prep: A cvt + W1 transpose + W2T ----
__global__ __launch_bounds__(256) void k_prep(const float* __restrict__ A,
                                              __bf16* __restrict__ Ab,
                                              const float* __restrict__ W1,
                                              __bf16* __restrict__ W1T,
                                              const float* __restrict__ W2,
                                              __bf16* __restrict__ W2T,
                                              int abase_blocks) {
  __shared__ float tile[32][33];
  const int bx  = blockIdx.x;
  const int tid = threadIdx.x;
  if (bx < abase_blocks) {
    // A [8192][9984] fp32 -> bf16, 8 elems/thread, fully coalesced
    const size_t t = (size_t)bx * 256 + tid;
    const float4* p = (const float4*)A + t * 2;
    const float4 a = p[0], b = p[1];
    bf16x8 o;
    o[0] = (__bf16)a.x; o[1] = (__bf16)a.y; o[2] = (__bf16)a.z; o[3] = (__bf16)a.w;
    o[4] = (__bf16)b.x; o[5] = (__bf16)b.y; o[6] = (__bf16)b.z; o[7] = (__bf16)b.w;
    *(bf16x8*)(Ab + t * 8) = o;
  } else if (bx < abase_blocks + 9984) {
    // W1 [9984][1000] -> W1T [1024][9984] bf16 (rows >=1000 zeroed)
    const int b = bx - abase_blocks;
    const int bk = b % 312, bn = b / 312;
    const int tx = tid & 31, ty = tid >> 5;
#pragma unroll
    for (int i = 0; i < 4; ++i) {
      const int kk = bk * 32 + ty + i * 8;
      const int nn = bn * 32 + tx;
      tile[ty + i * 8][tx] = (nn < 1000) ? W1[(size_t)kk * 1000 + nn] : 0.f;
    }
    __syncthreads();
#pragma unroll
    for (int i = 0; i < 4; ++i) {
      const int nn = bn * 32 + ty + i * 8;
      const int kk = bk * 32 + tx;
      W1T[(size_t)nn * D_DIM + kk] = (__bf16)tile[tx][ty + i * 8];
    }
  } else {
    // W2 [1000][40] -> W2T [64][1024] bf16 (pads zeroed)
    const int idx = (bx - abase_blocks - 9984) * 256 + tid;
    const int j = idx >> 10, k = idx & 1023;
    const float v = (j < 40 && k < 1000) ? W2[k * 40 + j] : 0.f;
    W2T[idx] = (__bf16)v;
  }
}

// ---- GEMM1 pipelined: h1 = relu(Ab @ W1T^T + b1) ----
// Round-0 addressing/grid + 4-deep LDS pipeline, counted vmcnt (never 0 in the
// main loop), ONE raw s_barrier per iter. STAGE(t+3) overwrites tile t-1's
// buffer, whose readers all passed this iteration's barrier. No lambdas:
// explicit macros keep the asm/builtin cluster on the plain codegen path.
__global__ __launch_bounds__(256) void k_gemm1p(const __bf16* __restrict__ A,
                                                const __bf16* __restrict__ BT,
                                                const float* __restrict__ b1,
                                                __bf16* __restrict__ C) {
  __shared__ __bf16 lds[4][8192];   // [buf][A 4096 el | B 4096 el] = 64 KiB
  const int tid  = threadIdx.x;
  const int lane = tid & 63;
  const int wid  = tid >> 6;
  const int tm = blockIdx.x, tn = blockIdx.y;  // tm fastest: 8 tn-readers of an
  const int wm = wid & 1, wn = wid >> 1;       // A-panel land on one XCD -> L2-hit

  // staging: wave w stages A-chunks 2w,2w+1 (16 rows x 32 cols each) + same for B
  const int c0 = wid * 2, c1 = c0 + 1;
  const int lr = lane >> 2;
  const int lc = (lane & 3) * 8;
  const __bf16* ag0 = A  + (size_t)(tm * 128 + c0 * 16 + lr) * D_DIM + lc;
  const __bf16* ag1 = A  + (size_t)(tm * 128 + c1 * 16 + lr) * D_DIM + lc;
  const __bf16* bg0 = BT + (size_t)(tn * 128 + c0 * 16 + lr) * D_DIM + lc;
  const __bf16* bg1 = BT + (size_t)(tn * 128 + c1 * 16 + lr) * D_DIM + lc;
  const int ao0 = c0 * 512, ao1 = c1 * 512;   // LDS element offsets (wave-uniform)

  const int fr = lane & 15;
  const int kq = (lane >> 4) * 8;
  f32x4 acc[4][4] = {};

#define STAGE(t) do {                                                \
    __bf16* L_ = &lds[(t) & 3][0];                                   \
    const size_t k0_ = (size_t)(t) * 32;                             \
    gld_lds16(ag0 + k0_, L_ + ao0);                                  \
    gld_lds16(ag1 + k0_, L_ + ao1);                                  \
    gld_lds16(bg0 + k0_, L_ + 4096 + ao0);                           \
    gld_lds16(bg1 + k0_, L_ + 4096 + ao1);                           \
  } while (0)

#define COMPUTE(t) do {                                              \
    const __bf16* L_ = &lds[(t) & 3][0];                             \
    bf16x8 af_[4], bf_[4];                                           \
    _Pragma("unroll")                                                \
    for (int mi = 0; mi < 4; ++mi)                                   \
      af_[mi] = *(const bf16x8*)&L_[(wm * 64 + mi * 16 + fr) * 32 + kq]; \
    _Pragma("unroll")                                                \
    for (int ni = 0; ni < 4; ++ni)                                   \
      bf_[ni] = *(const bf16x8*)&L_[4096 + (wn * 64 + ni * 16 + fr) * 32 + kq]; \
    __builtin_amdgcn_s_setprio(1);                                   \
    _Pragma("unroll")                                                \
    for (int mi = 0; mi < 4; ++mi)                                   \
      _Pragma("unroll")                                              \
      for (int ni = 0; ni < 4; ++ni)                                 \
        acc[mi][ni] = __builtin_amdgcn_mfma_f32_16x16x32_bf16(af_[mi], bf_[ni], acc[mi][ni], 0, 0, 0); \
    __builtin_amdgcn_s_setprio(0);                                   \
  } while (0)

  STAGE(0); STAGE(1); STAGE(2);
#pragma unroll 1
  for (int t = 0; t < 309; ++t) {
    WAITB(8);            // tile t landed; tiles t+1,t+2 (8 loads) stay in flight
    STAGE(t + 3);
    COMPUTE(t);
  }
  WAITB(8);  COMPUTE(309);
  WAITB(4);  COMPUTE(310);
  WAITB(0);  COMPUTE(311);

#undef STAGE
#undef COMPUTE

  // D layout: col=lane&15, row=(lane>>4)*4+reg  [m89]
  const int row0 = tm * 128 + wm * 64 + ((lane >> 4) << 2);
  const int col0 = tn * 128 + wn * 64 + fr;
#pragma unroll
  for (int ni = 0; ni < 4; ++ni) {
    const int col = col0 + ni * 16;
    const float bias = (col < 1000) ? b1[col] : 0.f;
#pragma unroll
    for (int mi = 0; mi < 4; ++mi)
#pragma unroll
      for (int r = 0; r < 4; ++r) {
        const float v = acc[mi][ni][r] + bias;
        C[(size_t)(row0 + mi * 16 + r) * H1P + col] = (__bf16)fmaxf(v, 0.f);
      }
  }
}

// ---- GEMM2 + logits fused (round-0 proven) ----
__global__ __launch_bounds__(256) void k_gemm2l(const __bf16* __restrict__ h1,
                                                const __bf16* __restrict__ W2T,
                                                const float* __restrict__ b2,
                                                const float* __restrict__ W3,
                                                const float* __restrict__ b3,
                                                float* __restrict__ lg) {
  __shared__ __align__(16) __bf16 As[2][64 * 32];
  __shared__ __align__(16) __bf16 Bs[2][64 * 32];
  const int tid  = threadIdx.x;
  const int lane = tid & 63;
  const int wid  = tid >> 6;
  const int bm   = blockIdx.x;

  const __bf16* ag = h1  + (size_t)(bm * 64 + wid * 16 + (lane >> 2)) * H1P + (lane & 3) * 8;
  const __bf16* bg = W2T + (size_t)(wid * 16 + (lane >> 2)) * H1P + (lane & 3) * 8;
  const int wo = wid * 16 * 32;

  const int fr = lane & 15;
  const int kq = (lane >> 4) * 8;
  f32x4 acc[4] = {};

  gld_lds16(ag, &As[0][wo]);
  gld_lds16(bg, &Bs[0][wo]);
  __syncthreads();

  for (int i = 0; i < 32; ++i) {
    const int cur = i & 1;
    if (i < 31) {
      gld_lds16(ag + (i + 1) * 32, &As[cur ^ 1][wo]);
      gld_lds16(bg + (i + 1) * 32, &Bs[cur ^ 1][wo]);
    }
    const bf16x8 a = *(const bf16x8*)&As[cur][(wid * 16 + fr) * 32 + kq];
#pragma unroll
    for (int ni = 0; ni < 4; ++ni) {
      const bf16x8 b = *(const bf16x8*)&Bs[cur][(ni * 16 + fr) * 32 + kq];
      acc[ni] = __builtin_amdgcn_mfma_f32_16x16x32_bf16(a, b, acc[ni], 0, 0, 0);
    }
    __syncthreads();
  }
  float s[4] = {0.f, 0.f, 0.f, 0.f};
#pragma unroll
  for (int ni = 0; ni < 4; ++ni) {
    const int j = ni * 16 + fr;
    if (j < 40) {
      const float w3 = W3[j], bias = b2[j];
#pragma unroll
      for (int r = 0; r < 4; ++r)
        s[r] += fmaxf(acc[ni][r] + bias, 0.f) * w3;
    }
  }
#pragma unroll
  for (int off = 1; off < 16; off <<= 1)
#pragma unroll
    for (int r = 0; r < 4; ++r)
      s[r] += __shfl_xor(s[r], off, 16);
  if (fr == 0) {
    const int m0 = bm * 64 + wid * 16 + ((lane >> 4) << 2);
    const float b3v = b3[0];
#pragma unroll
    for (int r = 0; r < 4; ++r)
      lg[m0 + r] = 1.f / (1.f + __expf(-(s[r] + b3v)));
  }
}

// ---- tiny-ws fallback GEMM1: fused-cvt from fp32 A (round-1, correct) ----
__global__ __launch_bounds__(256) void k_gemm1(const float* __restrict__ A,
                                               const __bf16* __restrict__ BT,
                                               const float* __restrict__ b1,
                                               __bf16* __restrict__ C) {
  __shared__ __bf16 As[128 * 32];
  __shared__ __bf16 Bs[128 * 32];
  const int tid  = threadIdx.x;
  const int lane = tid & 63;
  const int wid  = tid >> 6;
  const int tm = blockIdx.x, tn = blockIdx.y;
  const int wm = wid & 1, wn = wid >> 1;

  const int arow = tid >> 1;
  const int acol = (tid & 1) * 16;
  const float* ag = A + (size_t)(tm * 128 + arow) * D_DIM + acol;
  __bf16* asw = &As[arow * 32 + acol];

  const int c0 = wid * 2, c1 = wid * 2 + 1;
  const __bf16* bg0 = BT + (size_t)(tn * 128 + c0 * 16 + (lane >> 2)) * D_DIM + (lane & 3) * 8;
  const __bf16* bg1 = BT + (size_t)(tn * 128 + c1 * 16 + (lane >> 2)) * D_DIM + (lane & 3) * 8;
  __bf16* bl0 = &Bs[c0 * 16 * 32];
  __bf16* bl1 = &Bs[c1 * 16 * 32];

  const int fr = lane & 15;
  const int kq = (lane >> 4) * 8;
  f32x4 acc[4][4] = {};

  float4 pa[4];
  {
    const float4* ap = (const float4*)ag;
    pa[0] = ap[0]; pa[1] = ap[1]; pa[2] = ap[2]; pa[3] = ap[3];
  }
  for (int i = 0; i < 312; ++i) {
    const int k0 = i * 32;
    __syncthreads();
    {
      const float* pf = (const float*)pa;
      bf16x8 w0, w1;
#pragma unroll
      for (int j = 0; j < 8; ++j) { w0[j] = (__bf16)pf[j]; w1[j] = (__bf16)pf[j + 8]; }
      *(bf16x8*)asw       = w0;
      *(bf16x8*)(asw + 8) = w1;
    }
    gld_lds16(bg0 + k0, bl0);
    gld_lds16(bg1 + k0, bl1);
    __syncthreads();
    if (i != 311) {
      const float4* ap = (const float4*)(ag + k0 + 32);
      pa[0] = ap[0]; pa[1] = ap[1]; pa[2] = ap[2]; pa[3] = ap[3];
    }
    bf16x8 af[4], bfr[4];
#pragma unroll
    for (int mi = 0; mi < 4; ++mi)
      af[mi] = *(const bf16x8*)&As[(wm * 64 + mi * 16 + fr) * 32 + kq];
#pragma unroll
    for (int ni = 0; ni < 4; ++ni)
      bfr[ni] = *(const bf16x8*)&Bs[(wn * 64 + ni * 16 + fr) * 32 + kq];
#pragma unroll
    for (int mi = 0; mi < 4; ++mi)
#pragma unroll
      for (int ni = 0; ni < 4; ++ni)
        acc[mi][ni] = __builtin_amdgcn_mfma_f32_16x16x32_bf16(af[mi], bfr[ni], acc[mi][ni], 0, 0, 0);
  }
  const int row0 = tm * 128 + wm * 64 + ((lane >> 4) << 2);
  const int col0 = tn * 128 + wn * 64 + fr;
#pragma unroll
  for (int ni = 0; ni < 4; ++ni) {
    const int col = col0 + ni * 16;
    const float bias = (col < 1000) ? b1[col] : 0.f;
#pragma unroll
    for (int mi = 0; mi < 4; ++mi)
#pragma unroll
      for (int r = 0; r < 4; ++r) {
        const float v = acc[mi][ni][r] + bias;
        C[(size_t)(row0 + mi * 16 + r) * H1P + col] = (__bf16)fmaxf(v, 0.f);
      }
  }
}

// ---- ragged gather ----
__global__ void k_gather(const int* __restrict__ ts, const float* __restrict__ lg,
                         float* __restrict__ out) {
  const int t = blockIdx.x * 256 + threadIdx.x;
  const int b = t >> 9;
  const int s = ts[t];
  out[t] = (s > 0 && s < 512) ? lg[(b << 9) + s] : 0.f;
}

extern "C" void kernel_launch(void* const* d_in, const int* in_sizes, int n_in,
                              void* d_out, int out_size, void* d_ws, size_t ws_size,
                              hipStream_t stream) {
  const float* hs = (const float*)d_in[0];
  const int*   ts = (const int*)d_in[1];
  const float* W1 = (const float*)d_in[2];
  const float* b1 = (const float*)d_in[3];
  const float* W2 = (const float*)d_in[4];
  const float* b2 = (const float*)d_in[5];
  const float* W3 = (const float*)d_in[6];
  const float* b3 = (const float*)d_in[7];
  float* out = (float*)d_out;
  char* ws = (char*)d_ws;

  const size_t ABF   = 163577856;  // 8192*9984*2
  const size_t W1TSZ = 20447232;   // 1024*9984*2
  const size_t NEED  = ABF + W1TSZ + 16777216 + 131072 + 32768;  // ~191.7 MiB

  if (ws_size >= NEED) {
    __bf16* Ab  = (__bf16*)(ws);
    __bf16* W1T = (__bf16*)(ws + ABF);
    __bf16* h1  = (__bf16*)(ws + ABF + W1TSZ);
    __bf16* W2T = (__bf16*)(ws + ABF + W1TSZ + 16777216);
    float*  lg  = (float*) (ws + ABF + W1TSZ + 16777216 + 131072);

    k_prep<<<39936 + 9984 + 256, 256, 0, stream>>>(hs, Ab, W1, W1T, W2, W2T, 39936);
    k_gemm1p<<<dim3(64, 8), 256, 0, stream>>>(Ab, W1T, b1, h1);
    k_gemm2l<<<128, 256, 0, stream>>>(h1, W2T, b2, W3, b3, lg);
    k_gather<<<32, 256, 0, stream>>>(ts, lg, out);
  } else {
    // tiny-ws fallback: no Ab copy; fused-cvt gemm1
    __bf16* W1T = (__bf16*)(ws);
    __bf16* h1  = (__bf16*)(ws + W1TSZ);
    __bf16* W2T = (__bf16*)(ws + W1TSZ + 16777216);
    float*  lg  = (float*) (ws + W1TSZ + 16777216 + 131072);

    k_prep<<<9984 + 256, 256, 0, stream>>>(hs, (__bf16*)h1, W1, W1T, W2, W2T, 0);
    k_gemm1<<<dim3(64, 8), 256, 0, stream>>>(hs, W1T, b1, h1);
    k_gemm2l<<<128, 256, 0, stream>>>(h1, W2T, b2, W3, b3, lg);
    k_gather<<<32, 256, 0, stream>>>(ts, lg, out);
  }
}

// Round 5
// 703.265 us; speedup vs baseline: 1.3331x; 1.0039x over previous
//
#include <hip/hip_runtime.h>

typedef __bf16 bf16x8 __attribute__((ext_vector_type(8)));
typedef float  f32x4  __attribute__((ext_vector_type(4)));

#define D_DIM 9984   // 13*768
#define H1P   1024   // H1=1000 padded

__device__ __forceinline__ void gld_lds16(const void* g, void* l) {
  __builtin_amdgcn_global_load_lds((__attribute__((address_space(1))) void*)(g),
                                   (__attribute__((address_space(3))) void*)(l),
                                   16, 0, 0);
}

// counted-vmcnt barrier (T4, m218-proven pattern): wait until <=N outstanding
// VMEM ops, then raw barrier; sched_barrier(0) pins following code below it.
#define WAITB(N) do {                                              \
    asm volatile("s_waitcnt vmcnt(" #N ")" ::: "memory");          \
    __builtin_amdgcn_s_barrier();                                  \
    __builtin_amdgcn_sched_barrier(0);                             \
  } while (0)

// ---- merged prep: A cvt + W1 transpose + W2T ----
__global__ __launch_bounds__(256) void k_prep(const float* __restrict__ A,
                                              __bf16* __restrict__ Ab,
                                              const float* __restrict__ W1,
                                              __bf16* __restrict__ W1T,
                                              const float* __restrict__ W2,
                                              __bf16* __restrict__ W2T,
                                              int abase_blocks) {
  __shared__ float tile[32][33];
  const int bx  = blockIdx.x;
  const int tid = threadIdx.x;
  if (bx < abase_blocks) {
    // A [8192][9984] fp32 -> bf16, 8 elems/thread, fully coalesced
    const size_t t = (size_t)bx * 256 + tid;
    const float4* p = (const float4*)A + t * 2;
    const float4 a = p[0], b = p[1];
    bf16x8 o;
    o[0] = (__bf16)a.x; o[1] = (__bf16)a.y; o[2] = (__bf16)a.z; o[3] = (__bf16)a.w;
    o[4] = (__bf16)b.x; o[5] = (__bf16)b.y; o[6] = (__bf16)b.z; o[7] = (__bf16)b.w;
    *(bf16x8*)(Ab + t * 8) = o;
  } else if (bx < abase_blocks + 9984) {
    // W1 [9984][1000] -> W1T [1024][9984] bf16 (rows >=1000 zeroed)
    const int b = bx - abase_blocks;
    const int bk = b % 312, bn = b / 312;
    const int tx = tid & 31, ty = tid >> 5;
#pragma unroll
    for (int i = 0; i < 4; ++i) {
      const int kk = bk * 32 + ty + i * 8;
      const int nn = bn * 32 + tx;
      tile[ty + i * 8][tx] = (nn < 1000) ? W1[(size_t)kk * 1000 + nn] : 0.f;
    }
    __syncthreads();
#pragma unroll
    for (int i = 0; i < 4; ++i) {
      const int nn = bn * 32 + ty + i * 8;
      const int kk = bk * 32 + tx;
      W1T[(size_t)nn * D_DIM + kk] = (__bf16)tile[tx][ty + i * 8];
    }
  } else {
    // W2 [1000][40] -> W2T [64][1024] bf16 (pads zeroed)
    const int idx = (bx - abase_blocks - 9984) * 256 + tid;
    const int j = idx >> 10, k = idx & 1023;
    const float v = (j < 40 && k < 1000) ? W2[k * 40 + j] : 0.f;
    W2T[idx] = (__bf16)v;
  }
}

// ---- GEMM1 pipelined + LDS slot-swizzle: h1 = relu(Ab @ W1T^T + b1) ----
// Round-4 passed structure (4-deep pipeline, counted vmcnt, 1 raw barrier/iter)
// + T2-style bank-conflict fix. LDS row = 64 B (32 bf16) in four 16-B slots.
// Physical slot = logical slot ^ ((row>>1)&3), applied BOTH sides (rule #21):
//  - write side: gld_lds writes linearly, so lane l (LDS slot l&3 of row l>>2)
//    pre-swizzles its GLOBAL source column to logical slot (l&3)^((l>>3)&3);
//  - read side: fragment read uses slot (lane>>4)^((lane>>1)&3).
// Result: a 16-lane fragment-read group spreads over all 8 bank quads,
// 2 lanes/bank (free) instead of 8-way.
__global__ __launch_bounds__(256) void k_gemm1p(const __bf16* __restrict__ A,
                                                const __bf16* __restrict__ BT,
                                                const float* __restrict__ b1,
                                                __bf16* __restrict__ C) {
  __shared__ __bf16 lds[4][8192];   // [buf][A 4096 el | B 4096 el] = 64 KiB
  const int tid  = threadIdx.x;
  const int lane = tid & 63;
  const int wid  = tid >> 6;
  const int tm = blockIdx.x, tn = blockIdx.y;  // tm fastest: 8 tn-readers of an
  const int wm = wid & 1, wn = wid >> 1;       // A-panel land on one XCD -> L2-hit

  // staging: wave w stages A-chunks 2w,2w+1 (16 rows x 32 cols each) + same for B
  const int c0 = wid * 2, c1 = c0 + 1;
  const int lr = lane >> 2;
  const int lc = (((lane & 3) ^ ((lane >> 3) & 3)) * 8);   // swizzled source slot
  const __bf16* ag0 = A  + (size_t)(tm * 128 + c0 * 16 + lr) * D_DIM + lc;
  const __bf16* ag1 = A  + (size_t)(tm * 128 + c1 * 16 + lr) * D_DIM + lc;
  const __bf16* bg0 = BT + (size_t)(tn * 128 + c0 * 16 + lr) * D_DIM + lc;
  const __bf16* bg1 = BT + (size_t)(tn * 128 + c1 * 16 + lr) * D_DIM + lc;
  const int ao0 = c0 * 512, ao1 = c1 * 512;   // LDS element offsets (wave-uniform)

  const int fr  = lane & 15;
  const int kqs = (((lane >> 4) ^ ((lane >> 1) & 3)) * 8);  // swizzled read slot
  f32x4 acc[4][4] = {};

#define STAGE(t) do {                                                \
    __bf16* L_ = &lds[(t) & 3][0];                                   \
    const size_t k0_ = (size_t)(t) * 32;                             \
    gld_lds16(ag0 + k0_, L_ + ao0);                                  \
    gld_lds16(ag1 + k0_, L_ + ao1);                                  \
    gld_lds16(bg0 + k0_, L_ + 4096 + ao0);                           \
    gld_lds16(bg1 + k0_, L_ + 4096 + ao1);                           \
  } while (0)

#define COMPUTE(t) do {                                              \
    const __bf16* L_ = &lds[(t) & 3][0];                             \
    bf16x8 af_[4], bf_[4];                                           \
    _Pragma("unroll")                                                \
    for (int mi = 0; mi < 4; ++mi)                                   \
      af_[mi] = *(const bf16x8*)&L_[(wm * 64 + mi * 16 + fr) * 32 + kqs]; \
    _Pragma("unroll")                                                \
    for (int ni = 0; ni < 4; ++ni)                                   \
      bf_[ni] = *(const bf16x8*)&L_[4096 + (wn * 64 + ni * 16 + fr) * 32 + kqs]; \
    __builtin_amdgcn_s_setprio(1);                                   \
    _Pragma("unroll")                                                \
    for (int mi = 0; mi < 4; ++mi)                                   \
      _Pragma("unroll")                                              \
      for (int ni = 0; ni < 4; ++ni)                                 \
        acc[mi][ni] = __builtin_amdgcn_mfma_f32_16x16x32_bf16(af_[mi], bf_[ni], acc[mi][ni], 0, 0, 0); \
    __builtin_amdgcn_s_setprio(0);                                   \
  } while (0)

  STAGE(0); STAGE(1); STAGE(2);
#pragma unroll 1
  for (int t = 0; t < 309; ++t) {
    WAITB(8);            // tile t landed; tiles t+1,t+2 (8 loads) stay in flight
    STAGE(t + 3);
    COMPUTE(t);
  }
  WAITB(8);  COMPUTE(309);
  WAITB(4);  COMPUTE(310);
  WAITB(0);  COMPUTE(311);

#undef STAGE
#undef COMPUTE

  // D layout: col=lane&15, row=(lane>>4)*4+reg  [m89]
  const int row0 = tm * 128 + wm * 64 + ((lane >> 4) << 2);
  const int col0 = tn * 128 + wn * 64 + fr;
#pragma unroll
  for (int ni = 0; ni < 4; ++ni) {
    const int col = col0 + ni * 16;
    const float bias = (col < 1000) ? b1[col] : 0.f;
#pragma unroll
    for (int mi = 0; mi < 4; ++mi)
#pragma unroll
      for (int r = 0; r < 4; ++r) {
        const float v = acc[mi][ni][r] + bias;
        C[(size_t)(row0 + mi * 16 + r) * H1P + col] = (__bf16)fmaxf(v, 0.f);
      }
  }
}

// ---- GEMM2 + logits fused (round-0 proven) ----
__global__ __launch_bounds__(256) void k_gemm2l(const __bf16* __restrict__ h1,
                                                const __bf16* __restrict__ W2T,
                                                const float* __restrict__ b2,
                                                const float* __restrict__ W3,
                                                const float* __restrict__ b3,
                                                float* __restrict__ lg) {
  __shared__ __align__(16) __bf16 As[2][64 * 32];
  __shared__ __align__(16) __bf16 Bs[2][64 * 32];
  const int tid  = threadIdx.x;
  const int lane = tid & 63;
  const int wid  = tid >> 6;
  const int bm   = blockIdx.x;

  const __bf16* ag = h1  + (size_t)(bm * 64 + wid * 16 + (lane >> 2)) * H1P + (lane & 3) * 8;
  const __bf16* bg = W2T + (size_t)(wid * 16 + (lane >> 2)) * H1P + (lane & 3) * 8;
  const int wo = wid * 16 * 32;

  const int fr = lane & 15;
  const int kq = (lane >> 4) * 8;
  f32x4 acc[4] = {};

  gld_lds16(ag, &As[0][wo]);
  gld_lds16(bg, &Bs[0][wo]);
  __syncthreads();

  for (int i = 0; i < 32; ++i) {
    const int cur = i & 1;
    if (i < 31) {
      gld_lds16(ag + (i + 1) * 32, &As[cur ^ 1][wo]);
      gld_lds16(bg + (i + 1) * 32, &Bs[cur ^ 1][wo]);
    }
    const bf16x8 a = *(const bf16x8*)&As[cur][(wid * 16 + fr) * 32 + kq];
#pragma unroll
    for (int ni = 0; ni < 4; ++ni) {
      const bf16x8 b = *(const bf16x8*)&Bs[cur][(ni * 16 + fr) * 32 + kq];
      acc[ni] = __builtin_amdgcn_mfma_f32_16x16x32_bf16(a, b, acc[ni], 0, 0, 0);
    }
    __syncthreads();
  }
  float s[4] = {0.f, 0.f, 0.f, 0.f};
#pragma unroll
  for (int ni = 0; ni < 4; ++ni) {
    const int j = ni * 16 + fr;
    if (j < 40) {
      const float w3 = W3[j], bias = b2[j];
#pragma unroll
      for (int r = 0; r < 4; ++r)
        s[r] += fmaxf(acc[ni][r] + bias, 0.f) * w3;
    }
  }
#pragma unroll
  for (int off = 1; off < 16; off <<= 1)
#pragma unroll
    for (int r = 0; r < 4; ++r)
      s[r] += __shfl_xor(s[r], off, 16);
  if (fr == 0) {
    const int m0 = bm * 64 + wid * 16 + ((lane >> 4) << 2);
    const float b3v = b3[0];
#pragma unroll
    for (int r = 0; r < 4; ++r)
      lg[m0 + r] = 1.f / (1.f + __expf(-(s[r] + b3v)));
  }
}

// ---- tiny-ws fallback GEMM1: fused-cvt from fp32 A (round-1, correct) ----
__global__ __launch_bounds__(256) void k_gemm1(const float* __restrict__ A,
                                               const __bf16* __restrict__ BT,
                                               const float* __restrict__ b1,
                                               __bf16* __restrict__ C) {
  __shared__ __bf16 As[128 * 32];
  __shared__ __bf16 Bs[128 * 32];
  const int tid  = threadIdx.x;
  const int lane = tid & 63;
  const int wid  = tid >> 6;
  const int tm = blockIdx.x, tn = blockIdx.y;
  const int wm = wid & 1, wn = wid >> 1;

  const int arow = tid >> 1;
  const int acol = (tid & 1) * 16;
  const float* ag = A + (size_t)(tm * 128 + arow) * D_DIM + acol;
  __bf16* asw = &As[arow * 32 + acol];

  const int c0 = wid * 2, c1 = wid * 2 + 1;
  const __bf16* bg0 = BT + (size_t)(tn * 128 + c0 * 16 + (lane >> 2)) * D_DIM + (lane & 3) * 8;
  const __bf16* bg1 = BT + (size_t)(tn * 128 + c1 * 16 + (lane >> 2)) * D_DIM + (lane & 3) * 8;
  __bf16* bl0 = &Bs[c0 * 16 * 32];
  __bf16* bl1 = &Bs[c1 * 16 * 32];

  const int fr = lane & 15;
  const int kq = (lane >> 4) * 8;
  f32x4 acc[4][4] = {};

  float4 pa[4];
  {
    const float4* ap = (const float4*)ag;
    pa[0] = ap[0]; pa[1] = ap[1]; pa[2] = ap[2]; pa[3] = ap[3];
  }
  for (int i = 0; i < 312; ++i) {
    const int k0 = i * 32;
    __syncthreads();
    {
      const float* pf = (const float*)pa;
      bf16x8 w0, w1;
#pragma unroll
      for (int j = 0; j < 8; ++j) { w0[j] = (__bf16)pf[j]; w1[j] = (__bf16)pf[j + 8]; }
      *(bf16x8*)asw       = w0;
      *(bf16x8*)(asw + 8) = w1;
    }
    gld_lds16(bg0 + k0, bl0);
    gld_lds16(bg1 + k0, bl1);
    __syncthreads();
    if (i != 311) {
      const float4* ap = (const float4*)(ag + k0 + 32);
      pa[0] = ap[0]; pa[1] = ap[1]; pa[2] = ap[2]; pa[3] = ap[3];
    }
    bf16x8 af[4], bfr[4];
#pragma unroll
    for (int mi = 0; mi < 4; ++mi)
      af[mi] = *(const bf16x8*)&As[(wm * 64 + mi * 16 + fr) * 32 + kq];
#pragma unroll
    for (int ni = 0; ni < 4; ++ni)
      bfr[ni] = *(const bf16x8*)&Bs[(wn * 64 + ni * 16 + fr) * 32 + kq];
#pragma unroll
    for (int mi = 0; mi < 4; ++mi)
#pragma unroll
      for (int ni = 0; ni < 4; ++ni)
        acc[mi][ni] = __builtin_amdgcn_mfma_f32_16x16x32_bf16(af[mi], bfr[ni], acc[mi][ni], 0, 0, 0);
  }
  const int row0 = tm * 128 + wm * 64 + ((lane >> 4) << 2);
  const int col0 = tn * 128 + wn * 64 + fr;
#pragma unroll
  for (int ni = 0; ni < 4; ++ni) {
    const int col = col0 + ni * 16;
    const float bias = (col < 1000) ? b1[col] : 0.f;
#pragma unroll
    for (int mi = 0; mi < 4; ++mi)
#pragma unroll
      for (int r = 0; r < 4; ++r) {
        const float v = acc[mi][ni][r] + bias;
        C[(size_t)(row0 + mi * 16 + r) * H1P + col] = (__bf16)fmaxf(v, 0.f);
      }
  }
}

// ---- ragged gather ----
__global__ void k_gather(const int* __restrict__ ts, const float* __restrict__ lg,
                         float* __restrict__ out) {
  const int t = blockIdx.x * 256 + threadIdx.x;
  const int b = t >> 9;
  const int s = ts[t];
  out[t] = (s > 0 && s < 512) ? lg[(b << 9) + s] : 0.f;
}

extern "C" void kernel_launch(void* const* d_in, const int* in_sizes, int n_in,
                              void* d_out, int out_size, void* d_ws, size_t ws_size,
                              hipStream_t stream) {
  const float* hs = (const float*)d_in[0];
  const int*   ts = (const int*)d_in[1];
  const float* W1 = (const float*)d_in[2];
  const float* b1 = (const float*)d_in[3];
  const float* W2 = (const float*)d_in[4];
  const float* b2 = (const float*)d_in[5];
  const float* W3 = (const float*)d_in[6];
  const float* b3 = (const float*)d_in[7];
  float* out = (float*)d_out;
  char* ws = (char*)d_ws;

  const size_t ABF   = 163577856;  // 8192*9984*2
  const size_t W1TSZ = 20447232;   // 1024*9984*2
  const size_t NEED  = ABF + W1TSZ + 16777216 + 131072 + 32768;  // ~191.7 MiB

  if (ws_size >= NEED) {
    __bf16* Ab  = (__bf16*)(ws);
    __bf16* W1T = (__bf16*)(ws + ABF);
    __bf16* h1  = (__bf16*)(ws + ABF + W1TSZ);
    __bf16* W2T = (__bf16*)(ws + ABF + W1TSZ + 16777216);
    float*  lg  = (float*) (ws + ABF + W1TSZ + 16777216 + 131072);

    k_prep<<<39936 + 9984 + 256, 256, 0, stream>>>(hs, Ab, W1, W1T, W2, W2T, 39936);
    k_gemm1p<<<dim3(64, 8), 256, 0, stream>>>(Ab, W1T, b1, h1);
    k_gemm2l<<<128, 256, 0, stream>>>(h1, W2T, b2, W3, b3, lg);
    k_gather<<<32, 256, 0, stream>>>(ts, lg, out);
  } else {
    // tiny-ws fallback: no Ab copy; fused-cvt gemm1
    __bf16* W1T = (__bf16*)(ws);
    __bf16* h1  = (__bf16*)(ws + W1TSZ);
    __bf16* W2T = (__bf16*)(ws + W1TSZ + 16777216);
    float*  lg  = (float*) (ws + W1TSZ + 16777216 + 131072);

    k_prep<<<9984 + 256, 256, 0, stream>>>(hs, (__bf16*)h1, W1, W1T, W2, W2T, 0);
    k_gemm1<<<dim3(64, 8), 256, 0, stream>>>(hs, W1T, b1, h1);
    k_gemm2l<<<128, 256, 0, stream>>>(h1, W2T, b2, W3, b3, lg);
    k_gather<<<32, 256, 0, stream>>>(ts, lg, out);
  }
}